// Round 10
// baseline (853.209 us; speedup 1.0000x reference)
//
#include <hip/hip_runtime.h>
#include <stdint.h>

// VQ: bf16-MFMA candidate filter (+final-min compaction) + exact np-fp32
// select/overflow/gather pipeline. Selection is bit-identical to the R4
// kernel (absmax 32): the exact winner is provably inside the final key band
// (2B<=MARGIN proof); singleton band -> winner directly; multi -> identical
// R4 exact fmaf chain + first-index tie-break.
// R14: decompose the stubborn ~360us second phase (R9-R13 invariant) into
// vq_select (1 thr/token), vq_ovf (global queue, balanced 1 block/token),
// vq_gather (pure stream) so counters can attribute the residue; removes
// block-serial overflow scans (R12 counters: occ 15%, straggler profile).

#define NCODES 8192
#define DDIM   256
#define BT     65536

// legacy (R4) constants
#define TM     128
#define TN     128
#define NSEG   256
#define F4S    17

// new-path constants
#define CAPC   48
#define MARGIN 7e-4f          // proven bound 2B ~5.9e-4, headroom
#define TOKPB  128            // filter tokens per block
#define CCODES 64             // filter codes per chunk
#define CHUNKS 128            // 8192 / 64
#define KSCALE 1048576.0f     // 2^20 key quantization
#define KOFF   131072.0f      // 0.125 * 2^20
#define KMARG  737            // ceil(MARGIN*2^20)+3 slack
#define GBLK   32             // gather tokens per block

typedef float  f32x4  __attribute__((ext_vector_type(4)));
typedef __bf16 bf16x8 __attribute__((ext_vector_type(8)));

#define GLDS16(g, l) __builtin_amdgcn_global_load_lds(                         \
    (const __attribute__((address_space(1))) void*)(g),                        \
    (__attribute__((address_space(3))) void*)(l), 16, 0, 0)
#define GLDS4(g, l) __builtin_amdgcn_global_load_lds(                          \
    (const __attribute__((address_space(1))) void*)(g),                        \
    (__attribute__((address_space(3))) void*)(l), 4, 0, 0)

// order-preserving float->uint map (for LDS atomicMin on scores)
__device__ __forceinline__ unsigned int fenc(float f) {
  unsigned int u = __float_as_uint(f);
  return (u & 0x80000000u) ? ~u : (u | 0x80000000u);
}
__device__ __forceinline__ float fdec(unsigned int u) {
  unsigned int v = (u & 0x80000000u) ? (u ^ 0x80000000u) : ~u;
  return __uint_as_float(v);
}

// numpy pairwise_sum (scalar path) for n=256 over p_i = fl32(x_i*x_i).
__device__ __forceinline__ float np_pairwise256_sq(const float4* __restrict__ row) {
#pragma clang fp contract(off)
  float half[2];
  #pragma unroll
  for (int h = 0; h < 2; h++) {
    float r0,r1,r2,r3,r4,r5,r6,r7;
    float4 q0 = row[h*32 + 0];
    float4 q1 = row[h*32 + 1];
    r0 = q0.x*q0.x; r1 = q0.y*q0.y; r2 = q0.z*q0.z; r3 = q0.w*q0.w;
    r4 = q1.x*q1.x; r5 = q1.y*q1.y; r6 = q1.z*q1.z; r7 = q1.w*q1.w;
    #pragma unroll
    for (int g = 1; g < 16; g++) {
      q0 = row[h*32 + g*2];
      q1 = row[h*32 + g*2 + 1];
      r0 += q0.x*q0.x; r1 += q0.y*q0.y; r2 += q0.z*q0.z; r3 += q0.w*q0.w;
      r4 += q1.x*q1.x; r5 += q1.y*q1.y; r6 += q1.z*q1.z; r7 += q1.w*q1.w;
    }
    half[h] = ((r0+r1) + (r2+r3)) + ((r4+r5) + (r6+r7));
  }
  return half[0] + half[1];
}

// exact R4 scoring chain: ascending-k fmaf, fl(A-2B), fl(.+C); x from global
__device__ __forceinline__ float exact_score_g(const float4* __restrict__ xr,
                                               const float4* __restrict__ er,
                                               float Ar, float Cv) {
#pragma clang fp contract(off)
  float b = 0.0f;
  #pragma unroll 8
  for (int q = 0; q < 64; ++q) {
    const float4 xv = xr[q];
    const float4 ev = er[q];
    b = fmaf(xv.x, ev.x, b);
    b = fmaf(xv.y, ev.y, b);
    b = fmaf(xv.z, ev.z, b);
    b = fmaf(xv.w, ev.w, b);
  }
  const float t1 = fmaf(-2.0f, b, Ar);
  return t1 + Cv;
}

// two independent exact chains (ILP for the cooperative overflow scan)
__device__ __forceinline__ void exact_score2_g(const float4* __restrict__ xr,
                                               const float4* __restrict__ e1,
                                               const float4* __restrict__ e2,
                                               float Ar, float Cv1, float Cv2,
                                               float& s1, float& s2) {
#pragma clang fp contract(off)
  float b1 = 0.0f, b2 = 0.0f;
  #pragma unroll 8
  for (int q = 0; q < 64; ++q) {
    const float4 xv = xr[q];
    const float4 v1 = e1[q], v2 = e2[q];
    b1 = fmaf(xv.x, v1.x, b1); b2 = fmaf(xv.x, v2.x, b2);
    b1 = fmaf(xv.y, v1.y, b1); b2 = fmaf(xv.y, v2.y, b2);
    b1 = fmaf(xv.z, v1.z, b1); b2 = fmaf(xv.z, v2.z, b2);
    b1 = fmaf(xv.w, v1.w, b1); b2 = fmaf(xv.w, v2.w, b2);
  }
  s1 = fmaf(-2.0f, b1, Ar) + Cv1;
  s2 = fmaf(-2.0f, b2, Ar) + Cv2;
}

__global__ void vq_pre_a(const float* __restrict__ x, float* __restrict__ Astage) {
  const int t = blockIdx.x * 256 + threadIdx.x;
  Astage[t] = np_pairwise256_sq((const float4*)(x + (size_t)t * DDIM));
}

__global__ void vq_pre_c(const float* __restrict__ emb, float* __restrict__ Cws) {
  const int c = blockIdx.x * 256 + threadIdx.x;
  Cws[c] = np_pairwise256_sq((const float4*)(emb + (size_t)c * DDIM));
}

__global__ void vq_init(float* __restrict__ oloss) { *oloss = 0.0f; }

__global__ void vq_zq(int* __restrict__ qcnt) { *qcnt = 0; }

// emb fp32 -> bf16(RNE), stored XOR-swizzled so the filter's linear
// global_load_lds staging + swizzled ds_read_b128 is bank-conflict-free.
__global__ void vq_pre_e(const float* __restrict__ emb, uint4* __restrict__ ebf) {
  const int g   = blockIdx.x * 256 + threadIdx.x;   // 262144 total
  const int c   = g >> 5;
  const int blk = g & 31;
  const float4* e4 = (const float4*)(emb + (size_t)c * DDIM);
  float4 f0 = e4[blk*2], f1 = e4[blk*2 + 1];
  union { unsigned short us[8]; uint4 v; } pk;
  pk.us[0] = __builtin_bit_cast(unsigned short, (__bf16)f0.x);
  pk.us[1] = __builtin_bit_cast(unsigned short, (__bf16)f0.y);
  pk.us[2] = __builtin_bit_cast(unsigned short, (__bf16)f0.z);
  pk.us[3] = __builtin_bit_cast(unsigned short, (__bf16)f0.w);
  pk.us[4] = __builtin_bit_cast(unsigned short, (__bf16)f1.x);
  pk.us[5] = __builtin_bit_cast(unsigned short, (__bf16)f1.y);
  pk.us[6] = __builtin_bit_cast(unsigned short, (__bf16)f1.z);
  pk.us[7] = __builtin_bit_cast(unsigned short, (__bf16)f1.w);
  ebf[(size_t)c * 32 + (blk ^ (c & 7))] = pk.v;
}

// stage one 64-code chunk (32 KB) + its C values
__device__ __forceinline__ void stage_chunk(const char* __restrict__ ebf,
                                            const float* __restrict__ Cws,
                                            int ch, char* ebuf_dst,
                                            float* cs_dst, int tid) {
  const char* src = ebf + (size_t)ch * 32768 + (size_t)tid * 16;
  char* dst = ebuf_dst + (size_t)tid * 16;
  #pragma unroll
  for (int i = 0; i < 4; ++i) GLDS16(src + i * 8192, dst + i * 8192);
  if (tid < 64)
    GLDS4((const char*)Cws + (size_t)ch * 256 + (size_t)tid * 4,
          (char*)cs_dst + (size_t)tid * 4);
}

// ---------------- MFMA candidate filter (R9) + final-min compaction --------
__global__ __launch_bounds__(512, 4)
void vq_filter(const float* __restrict__ x, const char* __restrict__ ebf,
               const float* __restrict__ Cws, int* __restrict__ cntG,
               int* __restrict__ candG) {
  __shared__ __align__(16) char ebuf[2][32768];   // 64 KiB double buffer
  __shared__ float Cs[2][64];
  __shared__ unsigned int umin[TOKPB];            // cross-wave stale-safe min
  __shared__ int cntL[TOKPB];

  const int tid  = threadIdx.x;
  const int lane = tid & 63;
  const int wid  = tid >> 6;      // 0..7
  const int wm   = wid >> 2;      // 0..1  code half (32 codes)
  const int wn   = wid & 3;       // 0..3  token quarter (32 tokens)
  const int l15  = lane & 15;
  const int lhi  = lane >> 4;     // 0..3
  const int tok0 = blockIdx.x * TOKPB;

  if (tid < TOKPB) { umin[tid] = 0xFFFFFFFFu; cntL[tid] = 0; }

  // stage chunk 0 (overlaps the x-fragment loads below)
  stage_chunk(ebf, Cws, 0, ebuf[0], Cs[0], tid);

  // B-frags: x[token][k] bf16, K-resident. frag reg j = k = kk*32 + lhi*8 + j.
  const float4* x4 = (const float4*)x;
  bf16x8 xb[2][8];
  #pragma unroll
  for (int n = 0; n < 2; ++n) {
    const size_t trow = (size_t)(tok0 + wn * 32 + n * 16 + l15) * 64;
    #pragma unroll
    for (int kk = 0; kk < 8; ++kk) {
      float4 f0 = x4[trow + kk * 8 + lhi * 2];
      float4 f1 = x4[trow + kk * 8 + lhi * 2 + 1];
      bf16x8 v;
      v[0] = (__bf16)f0.x; v[1] = (__bf16)f0.y; v[2] = (__bf16)f0.z; v[3] = (__bf16)f0.w;
      v[4] = (__bf16)f1.x; v[5] = (__bf16)f1.y; v[6] = (__bf16)f1.z; v[7] = (__bf16)f1.w;
      xb[n][kk] = v;
    }
  }
  __syncthreads();   // staging + init visible

  const f32x4 zf = {0.f, 0.f, 0.f, 0.f};
  float rmin[2] = {1e30f, 1e30f};   // wave-group running min per n-tile

  for (int c = 0; c < CHUNKS; ++c) {
    // prefetch next chunk into the other buffers (wraps harmlessly at c=127)
    stage_chunk(ebf, Cws, (c + 1) & (CHUNKS - 1), ebuf[(c + 1) & 1],
                Cs[(c + 1) & 1], tid);

    const char* ecur = ebuf[c & 1];
    f32x4 acc[2][2];
    #pragma unroll
    for (int kk = 0; kk < 8; ++kk) {
      bf16x8 a[2];
      #pragma unroll
      for (int m = 0; m < 2; ++m) {
        const int row = wm * 32 + m * 16 + l15;
        const int blk = (kk * 4 + lhi) ^ (row & 7);
        a[m] = *(const bf16x8*)(ecur + row * 512 + blk * 16);
      }
      #pragma unroll
      for (int m = 0; m < 2; ++m)
        #pragma unroll
        for (int n = 0; n < 2; ++n)
          acc[m][n] = __builtin_amdgcn_mfma_f32_16x16x32_bf16(
              a[m], xb[n][kk], (kk == 0) ? zf : acc[m][n], 0, 0, 0);
    }

    // epilogue: s = C - 2P once per element; wave-min via shfl; rare atomicMin
    const float* Csc = Cs[c & 1];
    float cvals[2][4];
    #pragma unroll
    for (int m = 0; m < 2; ++m)
      #pragma unroll
      for (int r = 0; r < 4; ++r)
        cvals[m][r] = Csc[wm * 32 + m * 16 + lhi * 4 + r];

    #pragma unroll
    for (int n = 0; n < 2; ++n) {
      const int t = wn * 32 + n * 16 + l15;
      float s[8];
      float mn = 1e30f;
      #pragma unroll
      for (int m = 0; m < 2; ++m)
        #pragma unroll
        for (int r = 0; r < 4; ++r) {
          const float v = fmaf(-2.0f, acc[m][n][r], cvals[m][r]);
          s[m * 4 + r] = v;
          mn = fminf(mn, v);
        }
      // share chunk-min across the 4 lhi lanes of this token
      mn = fminf(mn, __shfl_xor(mn, 16));
      mn = fminf(mn, __shfl_xor(mn, 32));
      if (mn < rmin[n]) {            // uniform across the 4-lane group
        rmin[n] = mn;
        if (lhi == 0) atomicMin(&umin[t], fenc(mn));
      }
      // stale-safe cross-wave threshold (any observed umin >= final min)
      const float thr = fminf(rmin[n], fdec(umin[t])) + MARGIN;
      #pragma unroll
      for (int m = 0; m < 2; ++m)
        #pragma unroll
        for (int r = 0; r < 4; ++r) {
          if (s[m * 4 + r] <= thr) {
            const int code = c * CCODES + wm * 32 + m * 16 + lhi * 4 + r;
            int key = (int)fmaf(s[m * 4 + r], KSCALE, KOFF);  // 18-bit
            key = min(max(key, 0), 262143);
            const int pos = atomicAdd(&cntL[t], 1);
            if (pos < CAPC)
              candG[(size_t)(tok0 + t) * CAPC + pos] = (key << 13) | code;
          }
        }
    }

    __syncthreads();   // ebuf reads done + next-chunk staging drained
  }

  // ---- compaction: re-filter candidates against the FINAL min key band ----
  // umin[t] is final after the last barrier. Winner provably in band.
  {
    const int t4  = tid >> 2;           // 0..127 token in block
    const int j4  = tid & 3;
    const int cnt = cntL[t4];
    const int gt4 = tok0 + t4;
    int mask = 0, nk = 0;
    int ent[12];
    if (cnt <= CAPC) {
      const int keyF = min(max((int)fmaf(fdec(umin[t4]), KSCALE, KOFF), 0), 262143);
      const int thrk = keyF + KMARG;
      #pragma unroll
      for (int jj = 0; jj < 12; ++jj) {
        const int j = j4 + jj * 4;
        int e = 0;
        if (j < cnt) {
          e = candG[(size_t)gt4 * CAPC + j];
          if ((e >> 13) <= thrk) { mask |= 1 << jj; ++nk; }
        }
        ent[jj] = e;
      }
    }
    // exclusive prefix + total across the 4 lanes of this token
    const int b1 = __shfl_up(nk, 1, 4);
    const int b2 = __shfl_up(nk, 2, 4);
    const int b3 = __shfl_up(nk, 3, 4);
    const int base = ((j4 >= 1) ? b1 : 0) + ((j4 >= 2) ? b2 : 0)
                   + ((j4 >= 3) ? b3 : 0);
    int tot = nk;
    tot += __shfl_xor(tot, 1, 4);
    tot += __shfl_xor(tot, 2, 4);
    __syncthreads();                    // all reads done before rewrites
    if (cnt <= CAPC) {
      #pragma unroll
      for (int jj = 0; jj < 12; ++jj)
        if ((mask >> jj) & 1)
          candG[(size_t)gt4 * CAPC + base +
                __builtin_popcount(mask & ((1u << jj) - 1))] = ent[jj];
      if (j4 == 0) cntG[gt4] = tot;     // compact count (>=1, typ 1-3)
    } else if (j4 == 0) {
      cntG[gt4] = cnt;                  // >CAPC sentinel -> ovf queue
    }
  }
}

// ---------------- select: 1 thread/token, band exact-eval ----------------
__global__ __launch_bounds__(256, 8)
void vq_select(const float* __restrict__ x, const float* __restrict__ emb,
               const float* __restrict__ Cws, const int* __restrict__ cntG,
               const int* __restrict__ candG, float* __restrict__ oidx,
               int* __restrict__ queue, int* __restrict__ qcnt) {
  const int gt = blockIdx.x * 256 + threadIdx.x;
  const int cnt = cntG[gt];
  if (cnt > CAPC) {                     // rare: defer to balanced ovf kernel
    queue[atomicAdd(qcnt, 1)] = gt;
    return;
  }
  const int e0 = candG[(size_t)gt * CAPC] & 8191;
  if (cnt <= 1) {                       // singleton band IS the exact winner
    oidx[gt] = (float)(e0 + 1);
    return;
  }
  const float4* xr = (const float4*)x + (size_t)gt * 64;
  const float4* e4g = (const float4*)emb;
  const float Ar = np_pairwise256_sq(xr);
  float best = 1e30f; int bid = 0x7FFFFFFF;
  for (int j = 0; j < cnt; ++j) {       // 2..~4 chains, identical R4 exact
    const int c = candG[(size_t)gt * CAPC + j] & 8191;
    const float s = exact_score_g(xr, e4g + (size_t)c * 64, Ar, Cws[c]);
    if (s < best || (s == best && c < bid)) { best = s; bid = c; }
  }
  oidx[gt] = (float)(bid + 1);
}

// ---------------- ovf: balanced full scan, 1 block per queued token --------
__global__ __launch_bounds__(256, 4)
void vq_ovf(const float* __restrict__ x, const float* __restrict__ emb,
            const float* __restrict__ Cws, const int* __restrict__ queue,
            const int* __restrict__ qcnt, float* __restrict__ oidx) {
  __shared__ float rbv[256];
  __shared__ int   rbi[256];
  const int tid = threadIdx.x;
  const float4* e4g = (const float4*)emb;
  const int nq = *qcnt;
  for (int i = blockIdx.x; i < nq; i += gridDim.x) {
    const int gt = queue[i];
    const float4* xr = (const float4*)x + (size_t)gt * 64;
    const float At = np_pairwise256_sq(xr);   // identical on all lanes
    float bv = 1e30f; int bi2 = 0x7FFFFFFF;
    for (int c0 = tid; c0 < NCODES; c0 += 512) {
      const int c1 = c0 + 256;
      float s1, s2;
      exact_score2_g(xr, e4g + (size_t)c0 * 64, e4g + (size_t)c1 * 64,
                     At, Cws[c0], Cws[c1], s1, s2);
      if (s1 < bv || (s1 == bv && c0 < bi2)) { bv = s1; bi2 = c0; }
      if (s2 < bv || (s2 == bv && c1 < bi2)) { bv = s2; bi2 = c1; }
    }
    rbv[tid] = bv; rbi[tid] = bi2;
    __syncthreads();
    #pragma unroll
    for (int sft = 128; sft; sft >>= 1) {
      if (tid < sft) {
        const float v2 = rbv[tid + sft]; const int i2 = rbi[tid + sft];
        if (v2 < rbv[tid] || (v2 == rbv[tid] && i2 < rbi[tid])) {
          rbv[tid] = v2; rbi[tid] = i2;
        }
      }
      __syncthreads();
    }
    if (tid == 0) oidx[gt] = (float)(rbi[0] + 1);
    __syncthreads();                    // rbv/rbi reuse next iteration
  }
}

// ---------------- gather: pure stream y = emb[idx], loss partials ----------
__global__ __launch_bounds__(256, 8)
void vq_gather(const float* __restrict__ x, const float* __restrict__ emb,
               const float* __restrict__ oidx, float* __restrict__ y,
               float* __restrict__ lossP) {
  __shared__ int   idx_sh[GBLK];
  __shared__ float red[4];
  const int tid  = threadIdx.x;
  const int tok0 = blockIdx.x * GBLK;
  const float4* x4g = (const float4*)x;
  const float4* e4g = (const float4*)emb;

  if (tid < GBLK) idx_sh[tid] = (int)oidx[tok0 + tid] - 1;
  __syncthreads();

  float lsum = 0.0f;
  float4* y4 = (float4*)y;
  #pragma unroll
  for (int r = 0; r < 8; ++r) {
    const int g = tid + 256 * r, row = g >> 6, c4 = g & 63;
    const float4 ev = e4g[(size_t)idx_sh[row] * 64 + c4];
    const float4 xv = x4g[(size_t)(tok0 + row) * 64 + c4];
    y4[(size_t)(tok0 + row) * 64 + c4] = ev;
    const float dx = ev.x - xv.x, dy = ev.y - xv.y, dz = ev.z - xv.z, dw = ev.w - xv.w;
    lsum += dx * dx + dy * dy + dz * dz + dw * dw;
  }
  #pragma unroll
  for (int off = 32; off; off >>= 1) lsum += __shfl_down(lsum, off);
  if ((tid & 63) == 0) red[tid >> 6] = lsum;
  __syncthreads();
  if (tid == 0) lossP[blockIdx.x] = red[0] + red[1] + red[2] + red[3];
}

// n>0: sum n per-block partials then scale; n==0: scale the atomic total.
__global__ void vq_fin(float* __restrict__ oloss,
                       const float* __restrict__ lossP, int n) {
  __shared__ float sh[4];
  if (n > 0) {
    float s = 0.0f;
    for (int i = threadIdx.x; i < n; i += 256) s += lossP[i];
    #pragma unroll
    for (int off = 32; off; off >>= 1) s += __shfl_down(s, off);
    if ((threadIdx.x & 63) == 0) sh[threadIdx.x >> 6] = s;
    __syncthreads();
    if (threadIdx.x == 0)
      *oloss = (sh[0] + sh[1] + sh[2] + sh[3]) * (1.0f / 16777216.0f);
  } else {
    if (threadIdx.x == 0) *oloss = *oloss * (1.0f / 16777216.0f);
  }
}

// ---------------- legacy R4 path (fallback if workspace too small) ----------------
__global__ __launch_bounds__(256, 2)
void vq_main(const float* __restrict__ x, const float* __restrict__ emb,
             const float* __restrict__ Cws, float* __restrict__ y,
             float* __restrict__ oidx, float* __restrict__ oloss) {
  __shared__ float4 xs4[TM * F4S];
  __shared__ float4 es4[TN * F4S];
  __shared__ float  Cs[TN];
  __shared__ int    idx_sh[TM];
  __shared__ float  red[4];

  const int tid = threadIdx.x;
  const int ry = tid >> 4;
  const int rx = tid & 15;
  const int tok0 = blockIdx.x * TM;

  const float4* x4g = (const float4*)x;
  const float4* e4g = (const float4*)emb;

  float A_reg[8];
  #pragma unroll
  for (int m = 0; m < 8; m++) A_reg[m] = oidx[tok0 + ry + 16 * m];

  float best[8];
  int   i1[8];
  #pragma unroll
  for (int m = 0; m < 8; m++) { best[m] = 1e30f; i1[m] = 0; }

  float acc[8][8];

  for (int seg = 0; seg < NSEG; ++seg) {
    const int chunk = seg >> 2;
    const int kq = seg & 3;
    __syncthreads();
    #pragma unroll
    for (int h = 0; h < 2; h++) {
      float4 t[4];
      #pragma unroll
      for (int q = 0; q < 4; q++) {
        const int r = h * 4 + q;
        t[q] = x4g[(size_t)(tok0 + ry + 16 * r) * 64 + kq * 16 + rx];
      }
      #pragma unroll
      for (int q = 0; q < 4; q++) {
        const int r = h * 4 + q;
        xs4[(ry + 16 * r) * F4S + rx] = t[q];
      }
    }
    #pragma unroll
    for (int h = 0; h < 2; h++) {
      float4 t[4];
      #pragma unroll
      for (int q = 0; q < 4; q++) {
        const int r = h * 4 + q;
        t[q] = e4g[(size_t)(chunk * TN + ry + 16 * r) * 64 + kq * 16 + rx];
      }
      #pragma unroll
      for (int q = 0; q < 4; q++) {
        const int r = h * 4 + q;
        es4[(ry + 16 * r) * F4S + rx] = t[q];
      }
    }
    if (kq == 0 && tid < TN) Cs[tid] = Cws[chunk * TN + tid];
    __syncthreads();

    if (kq == 0) {
      #pragma unroll
      for (int m = 0; m < 8; m++)
        #pragma unroll
        for (int n = 0; n < 8; n++) acc[m][n] = 0.0f;
    }

    #pragma unroll
    for (int k4 = 0; k4 < 16; k4++) {
      float4 a[8], b[8];
      #pragma unroll
      for (int m = 0; m < 8; m++) a[m] = xs4[(ry + 16 * m) * F4S + k4];
      #pragma unroll
      for (int n = 0; n < 8; n++) b[n] = es4[(rx + 16 * n) * F4S + k4];
      #pragma unroll
      for (int m = 0; m < 8; m++)
        #pragma unroll
        for (int n = 0; n < 8; n++) {
          acc[m][n] = fmaf(a[m].x, b[n].x, acc[m][n]);
          acc[m][n] = fmaf(a[m].y, b[n].y, acc[m][n]);
          acc[m][n] = fmaf(a[m].z, b[n].z, acc[m][n]);
          acc[m][n] = fmaf(a[m].w, b[n].w, acc[m][n]);
        }
    }

    if (kq == 3) {
      const int c0 = chunk * TN;
      #pragma unroll
      for (int n = 0; n < 8; n++) {
        const float Cv = Cs[rx + 16 * n];
        const int c = c0 + rx + 16 * n;
        #pragma unroll
        for (int m = 0; m < 8; m++) {
          const float t1 = fmaf(-2.0f, acc[m][n], A_reg[m]);
          const float t2 = t1 + Cv;
          if (t2 < best[m]) { best[m] = t2; i1[m] = c; }
        }
      }
    }
  }

  __syncthreads();
  float* bv1 = (float*)xs4;
  int*   bi  = (int*)es4;
  #pragma unroll
  for (int m = 0; m < 8; m++) {
    bv1[(ry + 16 * m) * 16 + rx] = best[m];
    bi [(ry + 16 * m) * 16 + rx] = i1[m];
  }
  __syncthreads();
  if (tid < TM) {
    float v = bv1[tid * 16];
    int   id = bi[tid * 16];
    for (int t = 1; t < 16; t++) {
      const float vv = bv1[tid * 16 + t];
      const int   ii = bi [tid * 16 + t];
      if (vv < v || (vv == v && ii < id)) { v = vv; id = ii; }
    }
    idx_sh[tid] = id;
    oidx[tok0 + tid] = (float)(id + 1);
  }
  __syncthreads();

  float lsum = 0.0f;
  float4* y4 = (float4*)y;
  #pragma unroll
  for (int r = 0; r < 32; r++) {
    const int g = tid + 256 * r, row = g >> 6, c4 = g & 63;
    const float4 ev = e4g[(size_t)idx_sh[row] * 64 + c4];
    const float4 xv = x4g[(size_t)(tok0 + row) * 64 + c4];
    y4[(size_t)(tok0 + row) * 64 + c4] = ev;
    const float dx = ev.x - xv.x, dy = ev.y - xv.y, dz = ev.z - xv.z, dw = ev.w - xv.w;
    lsum += dx * dx + dy * dy + dz * dz + dw * dw;
  }
  #pragma unroll
  for (int off = 32; off; off >>= 1) lsum += __shfl_down(lsum, off);
  if ((tid & 63) == 0) red[tid >> 6] = lsum;
  __syncthreads();
  if (tid == 0) atomicAdd(oloss, red[0] + red[1] + red[2] + red[3]);
}

extern "C" void kernel_launch(void* const* d_in, const int* in_sizes, int n_in,
                              void* d_out, int out_size, void* d_ws, size_t ws_size,
                              hipStream_t stream) {
  const float* x   = (const float*)d_in[0];   // [16,4096,256]
  const float* emb = (const float*)d_in[1];   // [8192,256]

  float* y     = (float*)d_out;               // [16,4096,256]
  float* oidx  = y + (size_t)BT * DDIM;       // [16,4096] idx channel
  float* oloss = oidx + BT;                   // [1]

  // workspace layout
  char*  wsB   = (char*)d_ws;
  float* Cws   = (float*)wsB;                         //  32 KiB
  int*   cntG  = (int*)(wsB + 32768);                 // 256 KiB
  char*  ebf   = wsB + 32768 + 262144;                //   4 MiB bf16 swizzled emb
  int*   candG = (int*)(wsB + 294912 + 4194304);      //  12 MiB candidate lists
  // post-filter, the ebf region is dead -> reuse for queue/qcnt/lossP
  int*   queue = (int*)ebf;                           // 256 KiB (worst case)
  int*   qcnt  = (int*)(ebf + 262144);                // 4 B (padded)
  float* lossP = (float*)(ebf + 262400);              // 8 KiB (2048 partials)
  const size_t NEED = 294912 + 4194304 + (size_t)BT * CAPC * 4;  // 17072128 B

  vq_init <<<1, 1,           0, stream>>>(oloss);
  vq_pre_c<<<NCODES/256,256, 0, stream>>>(emb, Cws);

  if (ws_size >= NEED) {
    vq_pre_e <<<1024, 256, 0, stream>>>(emb, (uint4*)ebf);
    vq_filter<<<BT/TOKPB, 512, 0, stream>>>(x, ebf, Cws, cntG, candG);
    vq_zq    <<<1, 1, 0, stream>>>(qcnt);
    vq_select<<<BT/256, 256, 0, stream>>>(x, emb, Cws, cntG, candG,
                                          oidx, queue, qcnt);
    vq_ovf   <<<512, 256, 0, stream>>>(x, emb, Cws, queue, qcnt, oidx);
    vq_gather<<<BT/GBLK, 256, 0, stream>>>(x, emb, oidx, y, lossP);
    vq_fin   <<<1, 256, 0, stream>>>(oloss, lossP, BT / GBLK);
  } else {
    vq_pre_a<<<BT / 256, 256, 0, stream>>>(x, oidx);  // stage A in idx region
    vq_main <<<BT / TM, 256,  0, stream>>>(x, emb, Cws, y, oidx, oloss);
    vq_fin  <<<1, 256, 0, stream>>>(oloss, nullptr, 0);
  }
}

// Round 11
// 755.375 us; speedup vs baseline: 1.1295x; 1.1295x over previous
//
#include <hip/hip_runtime.h>
#include <stdint.h>

// VQ: bf16-MFMA candidate filter (+final-min compaction) + exact np-fp32
// finalize (R13 structure, best measured: 760us). Selection is bit-identical
// to the R4 kernel (absmax 32): exact winner provably inside the final key
// band (2B<=MARGIN proof); singleton band -> winner directly; multi ->
// identical R4 exact fmaf chain + first-index tie-break.
// R15: e-tile row stride 512 -> 528B (pad word rotates bank quads: 132 mod 32
// = 4 -> quad=(row+blk)%8) and LINEAR block layout (drop XOR swizzle) so the
// 8 kk-reads fold into ds_read_b128 offset immediates. Attacks the invariant
// SQ_LDS_BANK_CONFLICT=3.36e7 (~15% of filter cycles) + addressing VALU.

#define NCODES 8192
#define DDIM   256
#define BT     65536

// legacy (R4) constants
#define TM     128
#define TN     128
#define NSEG   256
#define F4S    17

// new-path constants
#define CAPC   48
#define MARGIN 7e-4f          // proven bound 2B ~5.9e-4, headroom
#define TOKPB  128            // filter tokens per block
#define CCODES 64             // filter codes per chunk
#define CHUNKS 128            // 8192 / 64
#define ESTR   528            // padded e-row stride (33 x 16B)
#define ECHB   33792          // 64 * 528 bytes per chunk
#define KSCALE 1048576.0f     // 2^20 key quantization
#define KOFF   131072.0f      // 0.125 * 2^20
#define KMARG  737            // ceil(MARGIN*2^20)+3 slack
#define FTOK   32             // finalize tokens per block

typedef float  f32x4  __attribute__((ext_vector_type(4)));
typedef __bf16 bf16x8 __attribute__((ext_vector_type(8)));

#define GLDS16(g, l) __builtin_amdgcn_global_load_lds(                         \
    (const __attribute__((address_space(1))) void*)(g),                        \
    (__attribute__((address_space(3))) void*)(l), 16, 0, 0)
#define GLDS4(g, l) __builtin_amdgcn_global_load_lds(                          \
    (const __attribute__((address_space(1))) void*)(g),                        \
    (__attribute__((address_space(3))) void*)(l), 4, 0, 0)

// order-preserving float->uint map (for LDS atomicMin on scores)
__device__ __forceinline__ unsigned int fenc(float f) {
  unsigned int u = __float_as_uint(f);
  return (u & 0x80000000u) ? ~u : (u | 0x80000000u);
}
__device__ __forceinline__ float fdec(unsigned int u) {
  unsigned int v = (u & 0x80000000u) ? (u ^ 0x80000000u) : ~u;
  return __uint_as_float(v);
}

// numpy pairwise_sum (scalar path) for n=256 over p_i = fl32(x_i*x_i).
__device__ __forceinline__ float np_pairwise256_sq(const float4* __restrict__ row) {
#pragma clang fp contract(off)
  float half[2];
  #pragma unroll
  for (int h = 0; h < 2; h++) {
    float r0,r1,r2,r3,r4,r5,r6,r7;
    float4 q0 = row[h*32 + 0];
    float4 q1 = row[h*32 + 1];
    r0 = q0.x*q0.x; r1 = q0.y*q0.y; r2 = q0.z*q0.z; r3 = q0.w*q0.w;
    r4 = q1.x*q1.x; r5 = q1.y*q1.y; r6 = q1.z*q1.z; r7 = q1.w*q1.w;
    #pragma unroll
    for (int g = 1; g < 16; g++) {
      q0 = row[h*32 + g*2];
      q1 = row[h*32 + g*2 + 1];
      r0 += q0.x*q0.x; r1 += q0.y*q0.y; r2 += q0.z*q0.z; r3 += q0.w*q0.w;
      r4 += q1.x*q1.x; r5 += q1.y*q1.y; r6 += q1.z*q1.z; r7 += q1.w*q1.w;
    }
    half[h] = ((r0+r1) + (r2+r3)) + ((r4+r5) + (r6+r7));
  }
  return half[0] + half[1];
}

// exact R4 scoring chain: ascending-k fmaf, fl(A-2B), fl(.+C); x from global
__device__ __forceinline__ float exact_score_g(const float4* __restrict__ xr,
                                               const float4* __restrict__ er,
                                               float Ar, float Cv) {
#pragma clang fp contract(off)
  float b = 0.0f;
  #pragma unroll 8
  for (int q = 0; q < 64; ++q) {
    const float4 xv = xr[q];
    const float4 ev = er[q];
    b = fmaf(xv.x, ev.x, b);
    b = fmaf(xv.y, ev.y, b);
    b = fmaf(xv.z, ev.z, b);
    b = fmaf(xv.w, ev.w, b);
  }
  const float t1 = fmaf(-2.0f, b, Ar);
  return t1 + Cv;
}

// two independent exact chains (ILP for the cooperative overflow scan)
__device__ __forceinline__ void exact_score2_g(const float4* __restrict__ xr,
                                               const float4* __restrict__ e1,
                                               const float4* __restrict__ e2,
                                               float Ar, float Cv1, float Cv2,
                                               float& s1, float& s2) {
#pragma clang fp contract(off)
  float b1 = 0.0f, b2 = 0.0f;
  #pragma unroll 8
  for (int q = 0; q < 64; ++q) {
    const float4 xv = xr[q];
    const float4 v1 = e1[q], v2 = e2[q];
    b1 = fmaf(xv.x, v1.x, b1); b2 = fmaf(xv.x, v2.x, b2);
    b1 = fmaf(xv.y, v1.y, b1); b2 = fmaf(xv.y, v2.y, b2);
    b1 = fmaf(xv.z, v1.z, b1); b2 = fmaf(xv.z, v2.z, b2);
    b1 = fmaf(xv.w, v1.w, b1); b2 = fmaf(xv.w, v2.w, b2);
  }
  s1 = fmaf(-2.0f, b1, Ar) + Cv1;
  s2 = fmaf(-2.0f, b2, Ar) + Cv2;
}

__global__ void vq_pre_a(const float* __restrict__ x, float* __restrict__ Astage) {
  const int t = blockIdx.x * 256 + threadIdx.x;
  Astage[t] = np_pairwise256_sq((const float4*)(x + (size_t)t * DDIM));
}

__global__ void vq_pre_c(const float* __restrict__ emb, float* __restrict__ Cws) {
  const int c = blockIdx.x * 256 + threadIdx.x;
  Cws[c] = np_pairwise256_sq((const float4*)(emb + (size_t)c * DDIM));
}

__global__ void vq_init(float* __restrict__ oloss) { *oloss = 0.0f; }

// emb fp32 -> bf16(RNE), stored LINEAR at 528B row stride (32 data blocks +
// 1 zero pad block). Padding rotates LDS bank quads; linearity lets the
// filter's kk-reads use constant ds_read offsets.
__global__ void vq_pre_e(const float* __restrict__ emb, char* __restrict__ ebf) {
  const int g = blockIdx.x * 256 + threadIdx.x;   // 8192 * 33 = 270336 total
  if (g >= NCODES * 33) return;
  const int c = g / 33;
  const int s = g - c * 33;
  uint4* dst = (uint4*)(ebf + (size_t)c * ESTR + (size_t)s * 16);
  if (s == 32) { *dst = make_uint4(0, 0, 0, 0); return; }
  const float4* e4 = (const float4*)(emb + (size_t)c * DDIM);
  float4 f0 = e4[s*2], f1 = e4[s*2 + 1];
  union { unsigned short us[8]; uint4 v; } pk;
  pk.us[0] = __builtin_bit_cast(unsigned short, (__bf16)f0.x);
  pk.us[1] = __builtin_bit_cast(unsigned short, (__bf16)f0.y);
  pk.us[2] = __builtin_bit_cast(unsigned short, (__bf16)f0.z);
  pk.us[3] = __builtin_bit_cast(unsigned short, (__bf16)f0.w);
  pk.us[4] = __builtin_bit_cast(unsigned short, (__bf16)f1.x);
  pk.us[5] = __builtin_bit_cast(unsigned short, (__bf16)f1.y);
  pk.us[6] = __builtin_bit_cast(unsigned short, (__bf16)f1.z);
  pk.us[7] = __builtin_bit_cast(unsigned short, (__bf16)f1.w);
  *dst = pk.v;
}

// stage one 64-code chunk (33792 B linear copy) + its C values
__device__ __forceinline__ void stage_chunk(const char* __restrict__ ebf,
                                            const float* __restrict__ Cws,
                                            int ch, char* ebuf_dst,
                                            float* cs_dst, int tid) {
  const char* src = ebf + (size_t)ch * ECHB;
  #pragma unroll
  for (int i = 0; i < 4; ++i)
    GLDS16(src + (size_t)tid * 16 + i * 8192, ebuf_dst + (size_t)tid * 16 + i * 8192);
  if (tid < 64)
    GLDS16(src + 32768 + (size_t)tid * 16, ebuf_dst + 32768 + (size_t)tid * 16);
  if (tid >= 64 && tid < 128)
    GLDS4((const char*)Cws + (size_t)ch * 256 + (size_t)(tid - 64) * 4,
          (char*)cs_dst + (size_t)(tid - 64) * 4);
}

// ---------------- MFMA candidate filter + final-min compaction ----------------
// D[code][token] = emb_bf16 . x_bf16^T; block 512 thr = 128 tokens; chunk 64
// codes; waves 2(wm) x 4(wn); wave tile 32x32; LDS ~69KB -> 2 blocks/CU.
__global__ __launch_bounds__(512, 4)
void vq_filter(const float* __restrict__ x, const char* __restrict__ ebf,
               const float* __restrict__ Cws, int* __restrict__ cntG,
               int* __restrict__ candG) {
  __shared__ __align__(16) char ebuf[2][ECHB];    // 66 KiB double buffer
  __shared__ float Cs[2][64];
  __shared__ unsigned int umin[TOKPB];            // cross-wave stale-safe min
  __shared__ int cntL[TOKPB];

  const int tid  = threadIdx.x;
  const int lane = tid & 63;
  const int wid  = tid >> 6;      // 0..7
  const int wm   = wid >> 2;      // 0..1  code half (32 codes)
  const int wn   = wid & 3;       // 0..3  token quarter (32 tokens)
  const int l15  = lane & 15;
  const int lhi  = lane >> 4;     // 0..3
  const int tok0 = blockIdx.x * TOKPB;

  if (tid < TOKPB) { umin[tid] = 0xFFFFFFFFu; cntL[tid] = 0; }

  // stage chunk 0 (overlaps the x-fragment loads below)
  stage_chunk(ebf, Cws, 0, ebuf[0], Cs[0], tid);

  // B-frags: x[token][k] bf16, K-resident. frag reg j = k = kk*32 + lhi*8 + j.
  const float4* x4 = (const float4*)x;
  bf16x8 xb[2][8];
  #pragma unroll
  for (int n = 0; n < 2; ++n) {
    const size_t trow = (size_t)(tok0 + wn * 32 + n * 16 + l15) * 64;
    #pragma unroll
    for (int kk = 0; kk < 8; ++kk) {
      float4 f0 = x4[trow + kk * 8 + lhi * 2];
      float4 f1 = x4[trow + kk * 8 + lhi * 2 + 1];
      bf16x8 v;
      v[0] = (__bf16)f0.x; v[1] = (__bf16)f0.y; v[2] = (__bf16)f0.z; v[3] = (__bf16)f0.w;
      v[4] = (__bf16)f1.x; v[5] = (__bf16)f1.y; v[6] = (__bf16)f1.z; v[7] = (__bf16)f1.w;
      xb[n][kk] = v;
    }
  }
  __syncthreads();   // staging + init visible

  const f32x4 zf = {0.f, 0.f, 0.f, 0.f};
  float rmin[2] = {1e30f, 1e30f};   // wave-group running min per n-tile

  for (int c = 0; c < CHUNKS; ++c) {
    // prefetch next chunk into the other buffers (wraps harmlessly at c=127)
    stage_chunk(ebf, Cws, (c + 1) & (CHUNKS - 1), ebuf[(c + 1) & 1],
                Cs[(c + 1) & 1], tid);

    const char* ecur = ebuf[c & 1];
    // per-operand base: linear layout -> kk folds into offset immediates
    const char* abase[2];
    #pragma unroll
    for (int m = 0; m < 2; ++m)
      abase[m] = ecur + (wm * 32 + m * 16 + l15) * ESTR + lhi * 16;

    f32x4 acc[2][2];
    #pragma unroll
    for (int kk = 0; kk < 8; ++kk) {
      bf16x8 a[2];
      #pragma unroll
      for (int m = 0; m < 2; ++m)
        a[m] = *(const bf16x8*)(abase[m] + kk * 64);
      #pragma unroll
      for (int m = 0; m < 2; ++m)
        #pragma unroll
        for (int n = 0; n < 2; ++n)
          acc[m][n] = __builtin_amdgcn_mfma_f32_16x16x32_bf16(
              a[m], xb[n][kk], (kk == 0) ? zf : acc[m][n], 0, 0, 0);
    }

    // epilogue: s = C - 2P once per element; wave-min via shfl; rare atomicMin
    const float* Csc = Cs[c & 1];
    float cvals[2][4];
    #pragma unroll
    for (int m = 0; m < 2; ++m)
      #pragma unroll
      for (int r = 0; r < 4; ++r)
        cvals[m][r] = Csc[wm * 32 + m * 16 + lhi * 4 + r];

    #pragma unroll
    for (int n = 0; n < 2; ++n) {
      const int t = wn * 32 + n * 16 + l15;
      float s[8];
      float mn = 1e30f;
      #pragma unroll
      for (int m = 0; m < 2; ++m)
        #pragma unroll
        for (int r = 0; r < 4; ++r) {
          const float v = fmaf(-2.0f, acc[m][n][r], cvals[m][r]);
          s[m * 4 + r] = v;
          mn = fminf(mn, v);
        }
      // share chunk-min across the 4 lhi lanes of this token
      mn = fminf(mn, __shfl_xor(mn, 16));
      mn = fminf(mn, __shfl_xor(mn, 32));
      if (mn < rmin[n]) {            // uniform across the 4-lane group
        rmin[n] = mn;
        if (lhi == 0) atomicMin(&umin[t], fenc(mn));
      }
      // stale-safe cross-wave threshold (any observed umin >= final min)
      const float thr = fminf(rmin[n], fdec(umin[t])) + MARGIN;
      #pragma unroll
      for (int m = 0; m < 2; ++m)
        #pragma unroll
        for (int r = 0; r < 4; ++r) {
          if (s[m * 4 + r] <= thr) {
            const int code = c * CCODES + wm * 32 + m * 16 + lhi * 4 + r;
            int key = (int)fmaf(s[m * 4 + r], KSCALE, KOFF);  // 18-bit
            key = min(max(key, 0), 262143);
            const int pos = atomicAdd(&cntL[t], 1);
            if (pos < CAPC)
              candG[(size_t)(tok0 + t) * CAPC + pos] = (key << 13) | code;
          }
        }
    }

    __syncthreads();   // ebuf reads done + next-chunk staging drained
  }

  // ---- compaction: re-filter candidates against the FINAL min key band ----
  // umin[t] is final after the last barrier. Winner provably in band.
  {
    const int t4  = tid >> 2;           // 0..127 token in block
    const int j4  = tid & 3;
    const int cnt = cntL[t4];
    const int gt4 = tok0 + t4;
    int mask = 0, nk = 0;
    int ent[12];
    if (cnt <= CAPC) {
      const int keyF = min(max((int)fmaf(fdec(umin[t4]), KSCALE, KOFF), 0), 262143);
      const int thrk = keyF + KMARG;
      #pragma unroll
      for (int jj = 0; jj < 12; ++jj) {
        const int j = j4 + jj * 4;
        int e = 0;
        if (j < cnt) {
          e = candG[(size_t)gt4 * CAPC + j];
          if ((e >> 13) <= thrk) { mask |= 1 << jj; ++nk; }
        }
        ent[jj] = e;
      }
    }
    // exclusive prefix + total across the 4 lanes of this token
    const int b1 = __shfl_up(nk, 1, 4);
    const int b2 = __shfl_up(nk, 2, 4);
    const int b3 = __shfl_up(nk, 3, 4);
    const int base = ((j4 >= 1) ? b1 : 0) + ((j4 >= 2) ? b2 : 0)
                   + ((j4 >= 3) ? b3 : 0);
    int tot = nk;
    tot += __shfl_xor(tot, 1, 4);
    tot += __shfl_xor(tot, 2, 4);
    __syncthreads();                    // all reads done before rewrites
    if (cnt <= CAPC) {
      #pragma unroll
      for (int jj = 0; jj < 12; ++jj)
        if ((mask >> jj) & 1)
          candG[(size_t)gt4 * CAPC + base +
                __builtin_popcount(mask & ((1u << jj) - 1))] = ent[jj];
      if (j4 == 0) cntG[gt4] = tot;     // compact count (>=1, typ 1-3)
    } else if (j4 == 0) {
      cntG[gt4] = cnt;                  // >CAPC sentinel -> coop scan
    }
  }
}

// ---------------- finalize: band exact-eval + gather + loss ----------------
// 2048 blocks x 256 thr (32 tokens, 8 lanes/token), 8 blocks/CU resident.
// cnt==1 (common) -> winner directly; else A + 1-3 exact chains (R4 exact).
__global__ __launch_bounds__(256, 8)
void vq_finalize(const float* __restrict__ x, const float* __restrict__ emb,
                 const float* __restrict__ Cws, const int* __restrict__ cntG,
                 const int* __restrict__ candG, float* __restrict__ y,
                 float* __restrict__ oidx, float* __restrict__ oloss,
                 float* __restrict__ lossP) {
  __shared__ int   idx_sh[FTOK];
  __shared__ int   ovf_list[FTOK];
  __shared__ int   n_ovf;
  __shared__ float rbv[256];
  __shared__ int   rbi[256];
  __shared__ float red[4];

  const int tid  = threadIdx.x;
  const int tok0 = blockIdx.x * FTOK;
  const float4* x4g = (const float4*)x;
  const float4* e4g = (const float4*)emb;

  if (tid == 0) n_ovf = 0;
  __syncthreads();

  const int t  = tid >> 3;       // 0..31
  const int j0 = tid & 7;
  const int gt = tok0 + t;
  const int cnt = cntG[gt];
  const float4* xr = x4g + (size_t)gt * 64;

  if (cnt <= CAPC) {
    if (cnt <= 1) {
      // unique band member IS the exact winner
      if (j0 == 0) {
        const int c = candG[(size_t)gt * CAPC] & 8191;
        idx_sh[t] = c; oidx[gt] = (float)(c + 1);
      }
    } else {
      // exact rescore of the 2..~4 band members, identical R4 arithmetic
      const float Ar = np_pairwise256_sq(xr);
      float best = 1e30f; int bid = 0x7FFFFFFF;
      for (int j = j0; j < cnt; j += 8) {
        const int c = candG[(size_t)gt * CAPC + j] & 8191;
        const float s = exact_score_g(xr, e4g + (size_t)c * 64, Ar, Cws[c]);
        if (s < best || (s == best && c < bid)) { best = s; bid = c; }
      }
      #pragma unroll
      for (int off = 1; off <= 4; off <<= 1) {
        const float ob = __shfl_xor(best, off);
        const int   oi = __shfl_xor(bid, off);
        if (ob < best || (ob == best && oi < bid)) { best = ob; bid = oi; }
      }
      if (j0 == 0) { idx_sh[t] = bid; oidx[gt] = (float)(bid + 1); }
    }
  } else if (j0 == 0) {            // rare: queue for cooperative scan
    ovf_list[atomicAdd(&n_ovf, 1)] = t;
  }
  __syncthreads();                 // idx_sh (normal) + ovf queue visible

  // cooperative full scan for overflow tokens: 256 threads, 2-way ILP
  for (int o = 0; o < n_ovf; ++o) {
    const int tt = ovf_list[o];
    const float4* xrr = x4g + (size_t)(tok0 + tt) * 64;
    const float At = np_pairwise256_sq(xrr);   // identical on all lanes
    float bv = 1e30f; int bi2 = 0x7FFFFFFF;
    for (int c0 = tid; c0 < NCODES; c0 += 512) {
      const int c1 = c0 + 256;
      float s1, s2;
      exact_score2_g(xrr, e4g + (size_t)c0 * 64, e4g + (size_t)c1 * 64,
                     At, Cws[c0], Cws[c1], s1, s2);
      if (s1 < bv || (s1 == bv && c0 < bi2)) { bv = s1; bi2 = c0; }
      if (s2 < bv || (s2 == bv && c1 < bi2)) { bv = s2; bi2 = c1; }
    }
    rbv[tid] = bv; rbi[tid] = bi2;
    __syncthreads();
    #pragma unroll
    for (int sft = 128; sft; sft >>= 1) {
      if (tid < sft) {
        const float v2 = rbv[tid + sft]; const int i2 = rbi[tid + sft];
        if (v2 < rbv[tid] || (v2 == rbv[tid] && i2 < rbi[tid])) {
          rbv[tid] = v2; rbi[tid] = i2;
        }
      }
      __syncthreads();
    }
    if (tid == 0) { idx_sh[tt] = rbi[0]; oidx[tok0 + tt] = (float)(rbi[0] + 1); }
    __syncthreads();
  }
  __syncthreads();                 // idx_sh complete

  // gather y = emb[idx], accumulate loss (fully coalesced, 1KB per wave)
  float lsum = 0.0f;
  float4* y4 = (float4*)y;
  #pragma unroll
  for (int r = 0; r < 8; ++r) {
    const int g = tid + 256 * r, row = g >> 6, c4 = g & 63;
    const float4 ev = e4g[(size_t)idx_sh[row] * 64 + c4];
    const float4 xv = x4g[(size_t)(tok0 + row) * 64 + c4];
    y4[(size_t)(tok0 + row) * 64 + c4] = ev;
    const float dx = ev.x - xv.x, dy = ev.y - xv.y, dz = ev.z - xv.z, dw = ev.w - xv.w;
    lsum += dx * dx + dy * dy + dz * dz + dw * dw;
  }
  #pragma unroll
  for (int off = 32; off; off >>= 1) lsum += __shfl_down(lsum, off);
  if ((tid & 63) == 0) red[tid >> 6] = lsum;
  __syncthreads();
  if (tid == 0) {
    const float s = red[0] + red[1] + red[2] + red[3];
    if (lossP) lossP[blockIdx.x] = s;
    else       atomicAdd(oloss, s);
  }
}

// n>0: sum n per-block partials then scale; n==0: scale the atomic total.
__global__ void vq_fin(float* __restrict__ oloss,
                       const float* __restrict__ lossP, int n) {
  __shared__ float sh[4];
  if (n > 0) {
    float s = 0.0f;
    for (int i = threadIdx.x; i < n; i += 256) s += lossP[i];
    #pragma unroll
    for (int off = 32; off; off >>= 1) s += __shfl_down(s, off);
    if ((threadIdx.x & 63) == 0) sh[threadIdx.x >> 6] = s;
    __syncthreads();
    if (threadIdx.x == 0)
      *oloss = (sh[0] + sh[1] + sh[2] + sh[3]) * (1.0f / 16777216.0f);
  } else {
    if (threadIdx.x == 0) *oloss = *oloss * (1.0f / 16777216.0f);
  }
}

// ---------------- legacy R4 path (fallback if workspace too small) ----------------
__global__ __launch_bounds__(256, 2)
void vq_main(const float* __restrict__ x, const float* __restrict__ emb,
             const float* __restrict__ Cws, float* __restrict__ y,
             float* __restrict__ oidx, float* __restrict__ oloss) {
  __shared__ float4 xs4[TM * F4S];
  __shared__ float4 es4[TN * F4S];
  __shared__ float  Cs[TN];
  __shared__ int    idx_sh[TM];
  __shared__ float  red[4];

  const int tid = threadIdx.x;
  const int ry = tid >> 4;
  const int rx = tid & 15;
  const int tok0 = blockIdx.x * TM;

  const float4* x4g = (const float4*)x;
  const float4* e4g = (const float4*)emb;

  float A_reg[8];
  #pragma unroll
  for (int m = 0; m < 8; m++) A_reg[m] = oidx[tok0 + ry + 16 * m];

  float best[8];
  int   i1[8];
  #pragma unroll
  for (int m = 0; m < 8; m++) { best[m] = 1e30f; i1[m] = 0; }

  float acc[8][8];

  for (int seg = 0; seg < NSEG; ++seg) {
    const int chunk = seg >> 2;
    const int kq = seg & 3;
    __syncthreads();
    #pragma unroll
    for (int h = 0; h < 2; h++) {
      float4 t[4];
      #pragma unroll
      for (int q = 0; q < 4; q++) {
        const int r = h * 4 + q;
        t[q] = x4g[(size_t)(tok0 + ry + 16 * r) * 64 + kq * 16 + rx];
      }
      #pragma unroll
      for (int q = 0; q < 4; q++) {
        const int r = h * 4 + q;
        xs4[(ry + 16 * r) * F4S + rx] = t[q];
      }
    }
    #pragma unroll
    for (int h = 0; h < 2; h++) {
      float4 t[4];
      #pragma unroll
      for (int q = 0; q < 4; q++) {
        const int r = h * 4 + q;
        t[q] = e4g[(size_t)(chunk * TN + ry + 16 * r) * 64 + kq * 16 + rx];
      }
      #pragma unroll
      for (int q = 0; q < 4; q++) {
        const int r = h * 4 + q;
        es4[(ry + 16 * r) * F4S + rx] = t[q];
      }
    }
    if (kq == 0 && tid < TN) Cs[tid] = Cws[chunk * TN + tid];
    __syncthreads();

    if (kq == 0) {
      #pragma unroll
      for (int m = 0; m < 8; m++)
        #pragma unroll
        for (int n = 0; n < 8; n++) acc[m][n] = 0.0f;
    }

    #pragma unroll
    for (int k4 = 0; k4 < 16; k4++) {
      float4 a[8], b[8];
      #pragma unroll
      for (int m = 0; m < 8; m++) a[m] = xs4[(ry + 16 * m) * F4S + k4];
      #pragma unroll
      for (int n = 0; n < 8; n++) b[n] = es4[(rx + 16 * n) * F4S + k4];
      #pragma unroll
      for (int m = 0; m < 8; m++)
        #pragma unroll
        for (int n = 0; n < 8; n++) {
          acc[m][n] = fmaf(a[m].x, b[n].x, acc[m][n]);
          acc[m][n] = fmaf(a[m].y, b[n].y, acc[m][n]);
          acc[m][n] = fmaf(a[m].z, b[n].z, acc[m][n]);
          acc[m][n] = fmaf(a[m].w, b[n].w, acc[m][n]);
        }
    }

    if (kq == 3) {
      const int c0 = chunk * TN;
      #pragma unroll
      for (int n = 0; n < 8; n++) {
        const float Cv = Cs[rx + 16 * n];
        const int c = c0 + rx + 16 * n;
        #pragma unroll
        for (int m = 0; m < 8; m++) {
          const float t1 = fmaf(-2.0f, acc[m][n], A_reg[m]);
          const float t2 = t1 + Cv;
          if (t2 < best[m]) { best[m] = t2; i1[m] = c; }
        }
      }
    }
  }

  __syncthreads();
  float* bv1 = (float*)xs4;
  int*   bi  = (int*)es4;
  #pragma unroll
  for (int m = 0; m < 8; m++) {
    bv1[(ry + 16 * m) * 16 + rx] = best[m];
    bi [(ry + 16 * m) * 16 + rx] = i1[m];
  }
  __syncthreads();
  if (tid < TM) {
    float v = bv1[tid * 16];
    int   id = bi[tid * 16];
    for (int t = 1; t < 16; t++) {
      const float vv = bv1[tid * 16 + t];
      const int   ii = bi [tid * 16 + t];
      if (vv < v || (vv == v && ii < id)) { v = vv; id = ii; }
    }
    idx_sh[tid] = id;
    oidx[tok0 + tid] = (float)(id + 1);
  }
  __syncthreads();

  float lsum = 0.0f;
  float4* y4 = (float4*)y;
  #pragma unroll
  for (int r = 0; r < 32; r++) {
    const int g = tid + 256 * r, row = g >> 6, c4 = g & 63;
    const float4 ev = e4g[(size_t)idx_sh[row] * 64 + c4];
    const float4 xv = x4g[(size_t)(tok0 + row) * 64 + c4];
    y4[(size_t)(tok0 + row) * 64 + c4] = ev;
    const float dx = ev.x - xv.x, dy = ev.y - xv.y, dz = ev.z - xv.z, dw = ev.w - xv.w;
    lsum += dx * dx + dy * dy + dz * dz + dw * dw;
  }
  #pragma unroll
  for (int off = 32; off; off >>= 1) lsum += __shfl_down(lsum, off);
  if ((tid & 63) == 0) red[tid >> 6] = lsum;
  __syncthreads();
  if (tid == 0) atomicAdd(oloss, red[0] + red[1] + red[2] + red[3]);
}

extern "C" void kernel_launch(void* const* d_in, const int* in_sizes, int n_in,
                              void* d_out, int out_size, void* d_ws, size_t ws_size,
                              hipStream_t stream) {
  const float* x   = (const float*)d_in[0];   // [16,4096,256]
  const float* emb = (const float*)d_in[1];   // [8192,256]

  float* y     = (float*)d_out;               // [16,4096,256]
  float* oidx  = y + (size_t)BT * DDIM;       // [16,4096] idx channel
  float* oloss = oidx + BT;                   // [1]

  // workspace layout
  char*  wsB   = (char*)d_ws;
  float* Cws   = (float*)wsB;                          //  32 KiB
  int*   cntG  = (int*)(wsB + 32768);                  // 256 KiB
  char*  ebf   = wsB + 32768 + 262144;                 // 4.33 MiB padded bf16 emb
  const size_t EBYTES = (size_t)NCODES * ESTR;         // 4,325,376
  int*   candG = (int*)(wsB + 294912 + EBYTES);        //  12 MiB candidate lists
  float* lossP = (float*)(wsB + 294912 + EBYTES + (size_t)BT * CAPC * 4);
  const size_t NEED  = 294912 + EBYTES + (size_t)BT * CAPC * 4;  // 17,203,200 B
  const size_t NEED2 = NEED + (size_t)(BT / FTOK) * 4;           // +8 KiB

  vq_init <<<1, 1,           0, stream>>>(oloss);
  vq_pre_c<<<NCODES/256,256, 0, stream>>>(emb, Cws);

  if (ws_size >= NEED) {
    float* lp = (ws_size >= NEED2) ? lossP : nullptr;
    vq_pre_e   <<<(NCODES*33 + 255)/256, 256, 0, stream>>>(emb, ebf);
    vq_filter  <<<BT/TOKPB, 512, 0, stream>>>(x, ebf, Cws, cntG, candG);
    vq_finalize<<<BT/FTOK, 256, 0, stream>>>(x, emb, Cws, cntG, candG,
                                             y, oidx, oloss, lp);
    vq_fin     <<<1, 256, 0, stream>>>(oloss, lp, lp ? (BT / FTOK) : 0);
  } else {
    vq_pre_a<<<BT / 256, 256, 0, stream>>>(x, oidx);  // stage A in idx region
    vq_main <<<BT / TM, 256,  0, stream>>>(x, emb, Cws, y, oidx, oloss);
    vq_fin  <<<1, 256, 0, stream>>>(oloss, nullptr, 0);
  }
}